// Round 1
// baseline (8921.862 us; speedup 1.0000x reference)
//
#include <hip/hip_runtime.h>

// ---- problem dims (fixed by reference) ----
#define V_ 30000
#define D_ 300
#define T_ 24
#define H_ 256
#define NT_ 6000
#define NU_ 4000
#define N_ 10000
#define F_ 512
#define Z_ 256
#define E_ 80000
#define B_ 2000
#define H1_ 64
#define H2_ 100
#define HEADS_ 8
#define E2_ (E_ + N_)   // edges + self loops = 90000

#define BM 64
#define BN 64
#define BKK 16

// ---------------- generic tiled f32 GEMM ----------------
// C[M,N] = A[M,K] * B (+bias). A row m base = (arow ? arow[m*astride] : m) * K.
// BT=true : B is (N,K) row-major (torch Linear weight, C = A @ B^T)
// BT=false: B is (K,N) row-major (C = A @ B)
template<bool BT>
__global__ __launch_bounds__(256) void gemm_kern(
    const float* __restrict__ A, const int* __restrict__ arow, int astride,
    const float* __restrict__ B, const float* __restrict__ bias,
    float* __restrict__ C, int M, int N, int K)
{
    __shared__ float As[BKK][BM + 4];
    __shared__ float Bs[BKK][BN + 4];
    const int bm = blockIdx.y * BM, bn = blockIdx.x * BN;
    const int tid = (int)threadIdx.x;
    const int tx = tid & 15, ty = tid >> 4;
    float acc[4][4] = {{0.f}};

    // A-load mapping: 64 rows x 16 k, 4 elems/thread (k-contiguous)
    const int alr = tid >> 2;
    const int alc = (tid & 3) * 4;
    int abase = -1;
    {
        int arowg = bm + alr;
        if (arowg < M) {
            int r = arow ? arow[arowg * astride] : arowg;
            abase = r * K;
        }
    }

    for (int k0 = 0; k0 < K; k0 += BKK) {
#pragma unroll
        for (int i = 0; i < 4; i++) {
            int k = k0 + alc + i;
            float v = 0.f;
            if (abase >= 0 && k < K) v = A[abase + k];
            As[alc + i][alr] = v;
        }
        if (BT) {
            const int bln = tid >> 2;
            const int blk = (tid & 3) * 4;
            int ng = bn + bln;
#pragma unroll
            for (int i = 0; i < 4; i++) {
                int k = k0 + blk + i;
                float v = 0.f;
                if (ng < N && k < K) v = B[ng * K + k];
                Bs[blk + i][bln] = v;
            }
        } else {
            const int blk = tid >> 4;
            const int bln = (tid & 15) * 4;
            int k = k0 + blk;
#pragma unroll
            for (int i = 0; i < 4; i++) {
                int ng = bn + bln + i;
                float v = 0.f;
                if (k < K && ng < N) v = B[k * N + ng];
                Bs[blk][bln + i] = v;
            }
        }
        __syncthreads();
#pragma unroll
        for (int kk = 0; kk < BKK; kk++) {
            float a[4], b[4];
#pragma unroll
            for (int i = 0; i < 4; i++) a[i] = As[kk][ty * 4 + i];
#pragma unroll
            for (int j = 0; j < 4; j++) b[j] = Bs[kk][tx * 4 + j];
#pragma unroll
            for (int i = 0; i < 4; i++)
#pragma unroll
                for (int j = 0; j < 4; j++)
                    acc[i][j] += a[i] * b[j];
        }
        __syncthreads();
    }

#pragma unroll
    for (int i = 0; i < 4; i++) {
        int row = bm + ty * 4 + i;
        if (row >= M) continue;
#pragma unroll
        for (int j = 0; j < 4; j++) {
            int col = bn + tx * 4 + j;
            if (col >= N) continue;
            float v = acc[i][j];
            if (bias) v += bias[col];
            C[row * N + col] = v;
        }
    }
}

// ---------------- small utility kernels ----------------
__global__ void copy_f32(const float* __restrict__ s, float* __restrict__ d, int n)
{
    int i = blockIdx.x * blockDim.x + threadIdx.x;
    if (i < n) d[i] = s[i];
}

__global__ void fill_zero(float* p, int n)
{
    int i = blockIdx.x * blockDim.x + threadIdx.x;
    if (i < n) p[i] = 0.f;
}

__global__ void bias_init(float* __restrict__ outp, const float* __restrict__ bias,
                          int rows, int cols)
{
    int i = blockIdx.x * blockDim.x + threadIdx.x;
    if (i < rows * cols) outp[i] = bias[i % cols];
}

// ---------------- GRU gate math (torch semantics) ----------------
__global__ void gru_gates(const float* __restrict__ gi, const float* __restrict__ gh,
                          float* __restrict__ h)
{
    int idx = blockIdx.x * blockDim.x + threadIdx.x;
    if (idx >= NT_ * H_) return;
    int m = idx >> 8, j = idx & 255;
    const float* gim = gi + m * (3 * H_);
    const float* ghm = gh + m * (3 * H_);
    float ir = gim[j], iz = gim[j + H_], inn = gim[j + 2 * H_];
    float hr = ghm[j], hz = ghm[j + H_], hn = ghm[j + 2 * H_];
    float r  = 1.f / (1.f + expf(-(ir + hr)));
    float zt = 1.f / (1.f + expf(-(iz + hz)));
    float n  = tanhf(inn + r * hn);
    float ho = h[idx];
    h[idx] = (1.f - zt) * n + zt * ho;
}

// ---------------- VAE ----------------
__global__ void vae_z_kl(const float* __restrict__ mu, const float* __restrict__ lv,
                         const float* __restrict__ eps, float* __restrict__ z_out,
                         float* __restrict__ kl_out)
{
    int idx = blockIdx.x * blockDim.x + threadIdx.x;
    float t = 0.f;
    if (idx < NU_ * Z_) {
        float m = mu[idx], l = lv[idx];
        float el = expf(l);
        z_out[idx] = m + expf(0.5f * l) * eps[idx];
        t = -0.5f * (1.f + l - m * m - el);
    }
    __shared__ float red[256];
    red[threadIdx.x] = t;
    __syncthreads();
    for (int s = 128; s > 0; s >>= 1) {
        if ((int)threadIdx.x < s) red[threadIdx.x] += red[threadIdx.x + s];
        __syncthreads();
    }
    if (threadIdx.x == 0) atomicAdd(kl_out, red[0] * (1.f / NU_));
}

__global__ void rec_loss_kern(const float* __restrict__ rec, const float* __restrict__ uf,
                              float* __restrict__ loss_out)
{
    int idx = blockIdx.x * blockDim.x + threadIdx.x;
    float t = 0.f;
    if (idx < NU_ * F_) {
        float d = rec[idx] - uf[idx];
        t = d * d;
    }
    __shared__ float red[256];
    red[threadIdx.x] = t;
    __syncthreads();
    for (int s = 128; s > 0; s >>= 1) {
        if ((int)threadIdx.x < s) red[threadIdx.x] += red[threadIdx.x + s];
        __syncthreads();
    }
    if (threadIdx.x == 0) atomicAdd(loss_out, red[0] * (1.f / (NU_ * F_)));
}

// ---------------- assemble x_in = [hn[:B], z, hn[B:]] ----------------
__global__ void assemble_xin(const float* __restrict__ h1, float* __restrict__ x_in)
{
    int idx = blockIdx.x * blockDim.x + threadIdx.x;
    if (idx >= NT_ * H_) return;
    int row = idx >> 8, col = idx & 255;
    int dst = (row < B_) ? row : (row + NU_);
    x_in[dst * H_ + col] = h1[idx];
}

// ---------------- GAT ----------------
__device__ __forceinline__ unsigned f2sortable(float f)
{
    unsigned u = __float_as_uint(f);
    return (u & 0x80000000u) ? ~u : (u | 0x80000000u);
}
__device__ __forceinline__ float sortable2f(unsigned u)
{
    return (u & 0x80000000u) ? __uint_as_float(u & 0x7FFFFFFFu) : __uint_as_float(~u);
}

__global__ void gat_attn_coef(const float* __restrict__ xp, const float* __restrict__ a_src,
                              const float* __restrict__ a_dst, float* __restrict__ asn,
                              float* __restrict__ adn, int heads, int C)
{
    int i = blockIdx.x * blockDim.x + threadIdx.x;
    if (i >= N_ * heads) return;
    int node = i / heads, h = i - node * heads;
    const float* x = xp + (node * heads + h) * C;
    float s = 0.f, d = 0.f;
    for (int c = 0; c < C; c++) {
        float v = x[c];
        s += v * a_src[h * C + c];
        d += v * a_dst[h * C + c];
    }
    asn[i] = s;
    adn[i] = d;
}

__device__ __forceinline__ void edge_sd(const int* __restrict__ ei, int e, int& s, int& d)
{
    if (e < E_) { s = ei[e]; d = ei[E_ + e]; }
    else        { s = d = e - E_; }
}

__global__ void gat_edge_logits(const int* __restrict__ ei, const float* __restrict__ asn,
                                const float* __restrict__ adn, float* __restrict__ ebuf,
                                unsigned* __restrict__ emax, int heads)
{
    int idx = blockIdx.x * blockDim.x + threadIdx.x;
    if (idx >= E2_ * heads) return;
    int e = idx / heads, h = idx - e * heads;
    int s, d; edge_sd(ei, e, s, d);
    float v = asn[s * heads + h] + adn[d * heads + h];
    v = (v > 0.f) ? v : 0.2f * v;   // leaky_relu(0.2)
    ebuf[idx] = v;
    atomicMax(emax + d * heads + h, f2sortable(v));
}

__global__ void gat_edge_exp(const int* __restrict__ ei, float* __restrict__ ebuf,
                             const unsigned* __restrict__ emax, float* __restrict__ den,
                             int heads)
{
    int idx = blockIdx.x * blockDim.x + threadIdx.x;
    if (idx >= E2_ * heads) return;
    int e = idx / heads, h = idx - e * heads;
    int s, d; edge_sd(ei, e, s, d);
    float ee = expf(ebuf[idx] - sortable2f(emax[d * heads + h]));
    ebuf[idx] = ee;
    atomicAdd(den + d * heads + h, ee);
}

__global__ void gat_edge_alpha(const int* __restrict__ ei, float* __restrict__ ebuf,
                               const float* __restrict__ den, int heads)
{
    int idx = blockIdx.x * blockDim.x + threadIdx.x;
    if (idx >= E2_ * heads) return;
    int e = idx / heads, h = idx - e * heads;
    int s, d; edge_sd(ei, e, s, d);
    ebuf[idx] = ebuf[idx] / den[d * heads + h];
}

__global__ void gat_edge_agg(const int* __restrict__ ei, const float* __restrict__ alpha,
                             const float* __restrict__ xp, float* __restrict__ outp,
                             int heads, int C)
{
    int idx = blockIdx.x * blockDim.x + threadIdx.x;
    int total = E2_ * heads * C;
    if (idx >= total) return;
    int c = idx % C;
    int t = idx / C;
    int h = t % heads;
    int e = t / heads;
    int s, d; edge_sd(ei, e, s, d);
    float a = alpha[e * heads + h];
    atomicAdd(outp + d * heads * C + h * C + c, xp[s * heads * C + h * C + c] * a);
}

// ---------------- launcher ----------------
extern "C" void kernel_launch(void* const* d_in, const int* in_sizes, int n_in,
                              void* d_out, int out_size, void* d_ws, size_t ws_size,
                              hipStream_t stream)
{
    const float* user_feats = (const float*)d_in[1];
    const int*   gnf        = (const int*)d_in[2];
    const int*   ei         = (const int*)d_in[3];
    const float* temb       = (const float*)d_in[4];
    const float* w_ih0      = (const float*)d_in[5];
    const float* w_hh0      = (const float*)d_in[6];
    const float* b_ih0      = (const float*)d_in[7];
    const float* b_hh0      = (const float*)d_in[8];
    const float* w_ih1      = (const float*)d_in[9];
    const float* w_hh1      = (const float*)d_in[10];
    const float* b_ih1      = (const float*)d_in[11];
    const float* b_hh1      = (const float*)d_in[12];
    const float* h0in       = (const float*)d_in[13];
    const float* w_mu       = (const float*)d_in[14];
    const float* b_mu       = (const float*)d_in[15];
    const float* w_lv       = (const float*)d_in[16];
    const float* b_lv       = (const float*)d_in[17];
    const float* w_dec      = (const float*)d_in[18];
    const float* b_dec      = (const float*)d_in[19];
    const float* veps       = (const float*)d_in[20];
    const float* w1         = (const float*)d_in[21];
    const float* a_src1     = (const float*)d_in[22];
    const float* a_dst1     = (const float*)d_in[23];
    const float* b1         = (const float*)d_in[24];
    const float* w2         = (const float*)d_in[25];
    const float* a_src2     = (const float*)d_in[26];
    const float* a_dst2     = (const float*)d_in[27];
    const float* b2         = (const float*)d_in[28];
    float* out = (float*)d_out;

    // ---- workspace layout (floats) ----
    float* ws = (float*)d_ws;
    size_t o = 0;
    float* hbuf = ws + o; o += (size_t)2 * NT_ * H_;          // h0 layer states (layer0, layer1 contiguous)
    // big region, reused: GRU gi/gh + VAE mu/lv/rec, then GAT xp1/x1/xp2
    float* big  = ws + o; o += (size_t)13312000;
    float* gi   = big;                       // NT_*3H = 4,608,000
    float* gh   = big + 4608000;             // 4,608,000
    float* mu   = big + 9216000;             // 1,024,000
    float* lv   = big + 10240000;            // 1,024,000
    float* rec  = big + 11264000;            // 2,048,000
    float* xp1  = big;                       // N_*512 = 5,120,000 (reuses gi/gh after GRU)
    float* x1   = big + 5120000;             // 5,120,000
    float* xp2  = big + 10240000;            // 1,000,000
    float* x_in = ws + o; o += (size_t)N_ * H_;               // 2,560,000
    unsigned* emax1 = (unsigned*)(ws + o); o += N_ * HEADS_;  // 80,000
    float* den1 = ws + o; o += N_ * HEADS_;                   // 80,000
    unsigned* emax2 = (unsigned*)(ws + o); o += N_;           // 10,000
    float* den2 = ws + o; o += N_;                            // 10,000
    float* e1   = ws + o; o += (size_t)E2_ * HEADS_;          // 720,000
    float* e2   = ws + o; o += E2_;                           // 90,000
    float* asn1 = ws + o; o += N_ * HEADS_;
    float* adn1 = ws + o; o += N_ * HEADS_;
    float* asn2 = ws + o; o += N_;
    float* adn2 = ws + o; o += N_;

    const int TB = 256;
    auto blocks = [](int n) { return (n + 255) / 256; };
    auto gemm_nt = [&](const float* A, const int* arow, int astride, const float* Bm,
                       const float* bias, float* C, int M, int N, int K) {
        dim3 g((N + BN - 1) / BN, (M + BM - 1) / BM);
        hipLaunchKernelGGL((gemm_kern<true>), g, dim3(TB), 0, stream,
                           A, arow, astride, Bm, bias, C, M, N, K);
    };
    auto gemm_nn = [&](const float* A, const float* Bm, const float* bias, float* C,
                       int M, int N, int K) {
        dim3 g((N + BN - 1) / BN, (M + BM - 1) / BM);
        hipLaunchKernelGGL((gemm_kern<false>), g, dim3(TB), 0, stream,
                           A, (const int*)nullptr, 0, Bm, bias, C, M, N, K);
    };

    // ---- init: zero atomic accumulators + loss slots, copy initial h ----
    hipLaunchKernelGGL(fill_zero, dim3(blocks(180000)), dim3(TB), 0, stream,
                       (float*)emax1, 180000);          // emax1,den1,emax2,den2 contiguous
    hipLaunchKernelGGL(fill_zero, dim3(1), dim3(TB), 0, stream, out + N_ * H2_, 2);
    hipLaunchKernelGGL(copy_f32, dim3(blocks(2 * NT_ * H_)), dim3(TB), 0, stream,
                       h0in, hbuf, 2 * NT_ * H_);

    // ---- VAE ----
    gemm_nt(user_feats, nullptr, 0, w_mu, b_mu, mu, NU_, Z_, F_);
    gemm_nt(user_feats, nullptr, 0, w_lv, b_lv, lv, NU_, Z_, F_);
    float* z = x_in + (size_t)B_ * H_;   // z occupies x_in rows [B_, B_+NU_)
    hipLaunchKernelGGL(vae_z_kl, dim3(blocks(NU_ * Z_)), dim3(TB), 0, stream,
                       mu, lv, veps, z, out + N_ * H2_);
    gemm_nt(z, nullptr, 0, w_dec, b_dec, rec, NU_, F_, Z_);
    hipLaunchKernelGGL(rec_loss_kern, dim3(blocks(NU_ * F_)), dim3(TB), 0, stream,
                       rec, user_feats, out + N_ * H2_ + 1);

    // ---- 2-layer GRU, interleaved over T ----
    float* h0buf = hbuf;
    float* h1buf = hbuf + (size_t)NT_ * H_;
    for (int t = 0; t < T_; t++) {
        // layer 0: gi = gather(emb, tokens[:,t]) @ w_ih0^T + b_ih0 ; gh = h0 @ w_hh0^T + b_hh0
        gemm_nt(temb, gnf + t, T_, w_ih0, b_ih0, gi, NT_, 3 * H_, D_);
        gemm_nt(h0buf, nullptr, 0, w_hh0, b_hh0, gh, NT_, 3 * H_, H_);
        hipLaunchKernelGGL(gru_gates, dim3(blocks(NT_ * H_)), dim3(TB), 0, stream,
                           gi, gh, h0buf);
        // layer 1: input = h0buf (out0[t])
        gemm_nt(h0buf, nullptr, 0, w_ih1, b_ih1, gi, NT_, 3 * H_, H_);
        gemm_nt(h1buf, nullptr, 0, w_hh1, b_hh1, gh, NT_, 3 * H_, H_);
        hipLaunchKernelGGL(gru_gates, dim3(blocks(NT_ * H_)), dim3(TB), 0, stream,
                           gi, gh, h1buf);
    }

    // ---- assemble x_in = [hn[:B], z, hn[B:]] (z already in place) ----
    hipLaunchKernelGGL(assemble_xin, dim3(blocks(NT_ * H_)), dim3(TB), 0, stream,
                       h1buf, x_in);

    // ---- GAT layer 1 (8 heads x 64, concat) ----
    gemm_nn(x_in, w1, nullptr, xp1, N_, HEADS_ * H1_, H_);
    hipLaunchKernelGGL(gat_attn_coef, dim3(blocks(N_ * HEADS_)), dim3(TB), 0, stream,
                       xp1, a_src1, a_dst1, asn1, adn1, HEADS_, H1_);
    hipLaunchKernelGGL(bias_init, dim3(blocks(N_ * HEADS_ * H1_)), dim3(TB), 0, stream,
                       x1, b1, N_, HEADS_ * H1_);
    hipLaunchKernelGGL(gat_edge_logits, dim3(blocks(E2_ * HEADS_)), dim3(TB), 0, stream,
                       ei, asn1, adn1, e1, emax1, HEADS_);
    hipLaunchKernelGGL(gat_edge_exp, dim3(blocks(E2_ * HEADS_)), dim3(TB), 0, stream,
                       ei, e1, emax1, den1, HEADS_);
    hipLaunchKernelGGL(gat_edge_alpha, dim3(blocks(E2_ * HEADS_)), dim3(TB), 0, stream,
                       ei, e1, den1, HEADS_);
    hipLaunchKernelGGL(gat_edge_agg, dim3(blocks(E2_ * HEADS_ * H1_)), dim3(TB), 0, stream,
                       ei, e1, xp1, x1, HEADS_, H1_);

    // ---- GAT layer 2 (1 head x 100, mean==identity) → writes final x2 into d_out ----
    gemm_nn(x1, w2, nullptr, xp2, N_, H2_, HEADS_ * H1_);
    hipLaunchKernelGGL(gat_attn_coef, dim3(blocks(N_)), dim3(TB), 0, stream,
                       xp2, a_src2, a_dst2, asn2, adn2, 1, H2_);
    hipLaunchKernelGGL(bias_init, dim3(blocks(N_ * H2_)), dim3(TB), 0, stream,
                       out, b2, N_, H2_);
    hipLaunchKernelGGL(gat_edge_logits, dim3(blocks(E2_)), dim3(TB), 0, stream,
                       ei, asn2, adn2, e2, emax2, 1);
    hipLaunchKernelGGL(gat_edge_exp, dim3(blocks(E2_)), dim3(TB), 0, stream,
                       ei, e2, emax2, den2, 1);
    hipLaunchKernelGGL(gat_edge_alpha, dim3(blocks(E2_)), dim3(TB), 0, stream,
                       ei, e2, den2, 1);
    hipLaunchKernelGGL(gat_edge_agg, dim3(blocks(E2_ * H2_)), dim3(TB), 0, stream,
                       ei, e2, xp2, out, 1, H2_);

    (void)in_sizes; (void)n_in; (void)out_size; (void)ws_size;
}

// Round 2
// 3129.834 us; speedup vs baseline: 2.8506x; 2.8506x over previous
//
#include <hip/hip_runtime.h>

// ---- problem dims (fixed by reference) ----
#define V_ 30000
#define D_ 300
#define DP_ 320         // D padded to multiple of 32 for MFMA K-loop
#define T_ 24
#define H_ 256
#define NT_ 6000
#define NU_ 4000
#define N_ 10000
#define F_ 512
#define Z_ 256
#define E_ 80000
#define B_ 2000
#define H1_ 64
#define H2_ 100
#define HEADS_ 8
#define E2_ (E_ + N_)   // edges + self loops = 90000

typedef __bf16 bf16_t;
typedef bf16_t bf16x8 __attribute__((ext_vector_type(8)));
typedef float  f32x4  __attribute__((ext_vector_type(4)));

// =======================================================================
// Fused GRU step: one block computes h_new for a 64-row x 32-col tile.
//   gi = A_i @ W_i^T   (A_i rows optionally gathered: embedding lookup)
//   gh = A_h @ W_h^T
//   h  = (1-z)*n + z*h_old   (torch GRU gate math), written f32 + bf16
// Block = 256 thr = 4 waves; wave w owns rows [bm+16w, bm+16w+16).
// For h-col slice [bn, bn+32) we need gate cols {bn+j, 256+bn+j, 512+bn+j}
// -> 3 gates x 2 nfrags x (gi,gh) = 12 MFMA accumulators / wave.
// MFMA 16x16x32 bf16: A[m=lane&15][k=quad*8+j], B[n=lane&15][k=quad*8+j],
// D col=lane&15 row=quad*4+reg  (all per cdna_hip_programming.md §3).
// =======================================================================
template<int KI>
__global__ __launch_bounds__(256) void gru_step_kern(
    const bf16_t* __restrict__ Ai, const int* __restrict__ gather, int gstride,
    const bf16_t* __restrict__ Wi, const float* __restrict__ b_ih,
    const bf16_t* __restrict__ Ah, const bf16_t* __restrict__ Wh,
    const float* __restrict__ b_hh,
    float* __restrict__ hf, bf16_t* __restrict__ hb_out)
{
    const int tid  = (int)threadIdx.x;
    const int wave = tid >> 6, lane = tid & 63;
    const int quad = lane >> 4, l16 = lane & 15;
    const int bm = blockIdx.y * 64 + wave * 16;
    const int bn = blockIdx.x * 32;

    int mrow = bm + l16;
    int mclamp = mrow < NT_ ? mrow : NT_ - 1;
    const bf16_t* aiRow;
    if (gather) {
        int tok = gather[(size_t)mclamp * gstride];
        aiRow = Ai + (size_t)tok * KI;
    } else {
        aiRow = Ai + (size_t)mclamp * KI;
    }
    const bf16_t* ahRow = Ah + (size_t)mclamp * H_;

    f32x4 acc_i[3][2], acc_h[3][2];
#pragma unroll
    for (int g = 0; g < 3; g++)
#pragma unroll
        for (int f = 0; f < 2; f++) {
            acc_i[g][f] = (f32x4){0.f, 0.f, 0.f, 0.f};
            acc_h[g][f] = (f32x4){0.f, 0.f, 0.f, 0.f};
        }

    // ---- GEMM 1: gi over K=KI ----
    for (int k0 = 0; k0 < KI; k0 += 32) {
        bf16x8 a = *(const bf16x8*)(aiRow + k0 + quad * 8);
#pragma unroll
        for (int g = 0; g < 3; g++)
#pragma unroll
            for (int f = 0; f < 2; f++) {
                int wr = g * H_ + bn + f * 16 + l16;
                bf16x8 b = *(const bf16x8*)(Wi + (size_t)wr * KI + k0 + quad * 8);
                acc_i[g][f] = __builtin_amdgcn_mfma_f32_16x16x32_bf16(a, b, acc_i[g][f], 0, 0, 0);
            }
    }
    // ---- GEMM 2: gh over K=H_ ----
    for (int k0 = 0; k0 < H_; k0 += 32) {
        bf16x8 a = *(const bf16x8*)(ahRow + k0 + quad * 8);
#pragma unroll
        for (int g = 0; g < 3; g++)
#pragma unroll
            for (int f = 0; f < 2; f++) {
                int wr = g * H_ + bn + f * 16 + l16;
                bf16x8 b = *(const bf16x8*)(Wh + (size_t)wr * H_ + k0 + quad * 8);
                acc_h[g][f] = __builtin_amdgcn_mfma_f32_16x16x32_bf16(a, b, acc_h[g][f], 0, 0, 0);
            }
    }

    // ---- gate epilogue (pure per-lane: gi/gh/h_old align elementwise) ----
#pragma unroll
    for (int f = 0; f < 2; f++) {
        int col = bn + f * 16 + l16;
        float bir = b_ih[col], biz = b_ih[H_ + col], bin = b_ih[2 * H_ + col];
        float bhr = b_hh[col], bhz = b_hh[H_ + col], bhn = b_hh[2 * H_ + col];
#pragma unroll
        for (int r = 0; r < 4; r++) {
            int m = bm + quad * 4 + r;
            if (m >= NT_) continue;
            float ir = acc_i[0][f][r] + bir, hr = acc_h[0][f][r] + bhr;
            float iz = acc_i[1][f][r] + biz, hz = acc_h[1][f][r] + bhz;
            float in_ = acc_i[2][f][r] + bin, hn = acc_h[2][f][r] + bhn;
            float rg = 1.f / (1.f + expf(-(ir + hr)));
            float zg = 1.f / (1.f + expf(-(iz + hz)));
            float ng = tanhf(in_ + rg * hn);
            size_t off = (size_t)m * H_ + col;
            float hnew = (1.f - zg) * ng + zg * hf[off];
            hf[off] = hnew;
            hb_out[off] = (bf16_t)hnew;
        }
    }
}

// ---------------- f32 -> bf16 conversion (with optional K padding) ----------------
__global__ void conv_pad_bf16(const float* __restrict__ in, bf16_t* __restrict__ outp,
                              int rows, int cin, int cout)
{
    int i = blockIdx.x * blockDim.x + threadIdx.x;
    if (i >= rows * cout) return;
    int r = i / cout, c = i - r * cout;
    outp[i] = (bf16_t)(c < cin ? in[r * cin + c] : 0.f);
}

__global__ void init_h(const float* __restrict__ h0in, float* __restrict__ h0f,
                       float* __restrict__ h1f, bf16_t* __restrict__ h0b,
                       bf16_t* __restrict__ h1b)
{
    int i = blockIdx.x * blockDim.x + threadIdx.x;
    if (i >= NT_ * H_) return;
    float a = h0in[i], b = h0in[NT_ * H_ + i];
    h0f[i] = a; h1f[i] = b;
    h0b[i] = (bf16_t)a; h1b[i] = (bf16_t)b;
}

// ---------------- generic tiled f32 GEMM (VAE + GAT) ----------------
#define BM 64
#define BN 64
#define BKK 16
template<bool BT>
__global__ __launch_bounds__(256) void gemm_kern(
    const float* __restrict__ A, const float* __restrict__ B,
    const float* __restrict__ bias, float* __restrict__ C, int M, int N, int K)
{
    __shared__ float As[BKK][BM + 4];
    __shared__ float Bs[BKK][BN + 4];
    const int bm = blockIdx.y * BM, bn = blockIdx.x * BN;
    const int tid = (int)threadIdx.x;
    const int tx = tid & 15, ty = tid >> 4;
    float acc[4][4] = {{0.f}};
    const int alr = tid >> 2;
    const int alc = (tid & 3) * 4;
    int abase = (bm + alr < M) ? (bm + alr) * K : -1;

    for (int k0 = 0; k0 < K; k0 += BKK) {
#pragma unroll
        for (int i = 0; i < 4; i++) {
            int k = k0 + alc + i;
            float v = 0.f;
            if (abase >= 0 && k < K) v = A[abase + k];
            As[alc + i][alr] = v;
        }
        if (BT) {
            const int bln = tid >> 2;
            const int blk = (tid & 3) * 4;
            int ng = bn + bln;
#pragma unroll
            for (int i = 0; i < 4; i++) {
                int k = k0 + blk + i;
                float v = 0.f;
                if (ng < N && k < K) v = B[ng * K + k];
                Bs[blk + i][bln] = v;
            }
        } else {
            const int blk = tid >> 4;
            const int bln = (tid & 15) * 4;
            int k = k0 + blk;
#pragma unroll
            for (int i = 0; i < 4; i++) {
                int ng = bn + bln + i;
                float v = 0.f;
                if (k < K && ng < N) v = B[k * N + ng];
                Bs[blk][bln + i] = v;
            }
        }
        __syncthreads();
#pragma unroll
        for (int kk = 0; kk < BKK; kk++) {
            float a[4], b[4];
#pragma unroll
            for (int i = 0; i < 4; i++) a[i] = As[kk][ty * 4 + i];
#pragma unroll
            for (int j = 0; j < 4; j++) b[j] = Bs[kk][tx * 4 + j];
#pragma unroll
            for (int i = 0; i < 4; i++)
#pragma unroll
                for (int j = 0; j < 4; j++)
                    acc[i][j] += a[i] * b[j];
        }
        __syncthreads();
    }
#pragma unroll
    for (int i = 0; i < 4; i++) {
        int row = bm + ty * 4 + i;
        if (row >= M) continue;
#pragma unroll
        for (int j = 0; j < 4; j++) {
            int col = bn + tx * 4 + j;
            if (col >= N) continue;
            float v = acc[i][j];
            if (bias) v += bias[col];
            C[row * N + col] = v;
        }
    }
}

// ---------------- small utility kernels ----------------
__global__ void fill_zero(float* p, int n)
{
    int i = blockIdx.x * blockDim.x + threadIdx.x;
    if (i < n) p[i] = 0.f;
}

__global__ void bias_init(float* __restrict__ outp, const float* __restrict__ bias,
                          int rows, int cols)
{
    int i = blockIdx.x * blockDim.x + threadIdx.x;
    if (i < rows * cols) outp[i] = bias[i % cols];
}

// ---------------- VAE ----------------
__global__ void vae_z_kl(const float* __restrict__ mu, const float* __restrict__ lv,
                         const float* __restrict__ eps, float* __restrict__ z_out,
                         float* __restrict__ kl_out)
{
    int idx = blockIdx.x * blockDim.x + threadIdx.x;
    float t = 0.f;
    if (idx < NU_ * Z_) {
        float m = mu[idx], l = lv[idx];
        float el = expf(l);
        z_out[idx] = m + expf(0.5f * l) * eps[idx];
        t = -0.5f * (1.f + l - m * m - el);
    }
    __shared__ float red[256];
    red[threadIdx.x] = t;
    __syncthreads();
    for (int s = 128; s > 0; s >>= 1) {
        if ((int)threadIdx.x < s) red[threadIdx.x] += red[threadIdx.x + s];
        __syncthreads();
    }
    if (threadIdx.x == 0) atomicAdd(kl_out, red[0] * (1.f / NU_));
}

__global__ void rec_loss_kern(const float* __restrict__ rec, const float* __restrict__ uf,
                              float* __restrict__ loss_out)
{
    int idx = blockIdx.x * blockDim.x + threadIdx.x;
    float t = 0.f;
    if (idx < NU_ * F_) {
        float d = rec[idx] - uf[idx];
        t = d * d;
    }
    __shared__ float red[256];
    red[threadIdx.x] = t;
    __syncthreads();
    for (int s = 128; s > 0; s >>= 1) {
        if ((int)threadIdx.x < s) red[threadIdx.x] += red[threadIdx.x + s];
        __syncthreads();
    }
    if (threadIdx.x == 0) atomicAdd(loss_out, red[0] * (1.f / (NU_ * F_)));
}

// ---------------- assemble x_in = [hn[:B], z, hn[B:]] ----------------
__global__ void assemble_xin(const float* __restrict__ h1, float* __restrict__ x_in)
{
    int idx = blockIdx.x * blockDim.x + threadIdx.x;
    if (idx >= NT_ * H_) return;
    int row = idx >> 8, col = idx & 255;
    int dst = (row < B_) ? row : (row + NU_);
    x_in[dst * H_ + col] = h1[idx];
}

// ---------------- GAT ----------------
__device__ __forceinline__ unsigned f2sortable(float f)
{
    unsigned u = __float_as_uint(f);
    return (u & 0x80000000u) ? ~u : (u | 0x80000000u);
}
__device__ __forceinline__ float sortable2f(unsigned u)
{
    return (u & 0x80000000u) ? __uint_as_float(u & 0x7FFFFFFFu) : __uint_as_float(~u);
}

__global__ void gat_attn_coef(const float* __restrict__ xp, const float* __restrict__ a_src,
                              const float* __restrict__ a_dst, float* __restrict__ asn,
                              float* __restrict__ adn, int heads, int C)
{
    int i = blockIdx.x * blockDim.x + threadIdx.x;
    if (i >= N_ * heads) return;
    int node = i / heads, h = i - node * heads;
    const float* x = xp + (size_t)(node * heads + h) * C;
    float s = 0.f, d = 0.f;
    for (int c = 0; c < C; c++) {
        float v = x[c];
        s += v * a_src[h * C + c];
        d += v * a_dst[h * C + c];
    }
    asn[i] = s;
    adn[i] = d;
}

__device__ __forceinline__ void edge_sd(const int* __restrict__ ei, int e, int& s, int& d)
{
    if (e < E_) { s = ei[e]; d = ei[E_ + e]; }
    else        { s = d = e - E_; }
}

__global__ void gat_edge_logits(const int* __restrict__ ei, const float* __restrict__ asn,
                                const float* __restrict__ adn, float* __restrict__ ebuf,
                                unsigned* __restrict__ emax, int heads)
{
    int idx = blockIdx.x * blockDim.x + threadIdx.x;
    if (idx >= E2_ * heads) return;
    int e = idx / heads, h = idx - e * heads;
    int s, d; edge_sd(ei, e, s, d);
    float v = asn[s * heads + h] + adn[d * heads + h];
    v = (v > 0.f) ? v : 0.2f * v;
    ebuf[idx] = v;
    atomicMax(emax + d * heads + h, f2sortable(v));
}

__global__ void gat_edge_exp(const int* __restrict__ ei, float* __restrict__ ebuf,
                             const unsigned* __restrict__ emax, float* __restrict__ den,
                             int heads)
{
    int idx = blockIdx.x * blockDim.x + threadIdx.x;
    if (idx >= E2_ * heads) return;
    int e = idx / heads, h = idx - e * heads;
    int s, d; edge_sd(ei, e, s, d);
    float ee = expf(ebuf[idx] - sortable2f(emax[d * heads + h]));
    ebuf[idx] = ee;
    atomicAdd(den + d * heads + h, ee);
}

__global__ void gat_edge_alpha(const int* __restrict__ ei, float* __restrict__ ebuf,
                               const float* __restrict__ den, int heads)
{
    int idx = blockIdx.x * blockDim.x + threadIdx.x;
    if (idx >= E2_ * heads) return;
    int e = idx / heads, h = idx - e * heads;
    int s, d; edge_sd(ei, e, s, d);
    ebuf[idx] = ebuf[idx] / den[d * heads + h];
}

__global__ void gat_edge_agg(const int* __restrict__ ei, const float* __restrict__ alpha,
                             const float* __restrict__ xp, float* __restrict__ outp,
                             int heads, int C)
{
    int idx = blockIdx.x * blockDim.x + threadIdx.x;
    int total = E2_ * heads * C;
    if (idx >= total) return;
    int c = idx % C;
    int t = idx / C;
    int h = t % heads;
    int e = t / heads;
    int s, d; edge_sd(ei, e, s, d);
    float a = alpha[e * heads + h];
    atomicAdd(outp + (size_t)d * heads * C + h * C + c,
              xp[(size_t)s * heads * C + h * C + c] * a);
}

// ---------------- launcher ----------------
extern "C" void kernel_launch(void* const* d_in, const int* in_sizes, int n_in,
                              void* d_out, int out_size, void* d_ws, size_t ws_size,
                              hipStream_t stream)
{
    const float* user_feats = (const float*)d_in[1];
    const int*   gnf        = (const int*)d_in[2];
    const int*   ei         = (const int*)d_in[3];
    const float* temb       = (const float*)d_in[4];
    const float* w_ih0      = (const float*)d_in[5];
    const float* w_hh0      = (const float*)d_in[6];
    const float* b_ih0      = (const float*)d_in[7];
    const float* b_hh0      = (const float*)d_in[8];
    const float* w_ih1      = (const float*)d_in[9];
    const float* w_hh1      = (const float*)d_in[10];
    const float* b_ih1      = (const float*)d_in[11];
    const float* b_hh1      = (const float*)d_in[12];
    const float* h0in       = (const float*)d_in[13];
    const float* w_mu       = (const float*)d_in[14];
    const float* b_mu       = (const float*)d_in[15];
    const float* w_lv       = (const float*)d_in[16];
    const float* b_lv       = (const float*)d_in[17];
    const float* w_dec      = (const float*)d_in[18];
    const float* b_dec      = (const float*)d_in[19];
    const float* veps       = (const float*)d_in[20];
    const float* w1         = (const float*)d_in[21];
    const float* a_src1     = (const float*)d_in[22];
    const float* a_dst1     = (const float*)d_in[23];
    const float* b1         = (const float*)d_in[24];
    const float* w2         = (const float*)d_in[25];
    const float* a_src2     = (const float*)d_in[26];
    const float* a_dst2     = (const float*)d_in[27];
    const float* b2         = (const float*)d_in[28];
    float* out = (float*)d_out;

    // ---- workspace layout (floats) ----
    float* ws = (float*)d_ws;
    size_t o = 0;
    float*  h0f = ws + o; o += (size_t)NT_ * H_;              // 1,536,000
    float*  h1f = ws + o; o += (size_t)NT_ * H_;
    bf16_t* h0b[2]; bf16_t* h1b[2];
    h0b[0] = (bf16_t*)(ws + o); o += (size_t)NT_ * H_ / 2;    // bf16 = half floats
    h0b[1] = (bf16_t*)(ws + o); o += (size_t)NT_ * H_ / 2;
    h1b[0] = (bf16_t*)(ws + o); o += (size_t)NT_ * H_ / 2;
    h1b[1] = (bf16_t*)(ws + o); o += (size_t)NT_ * H_ / 2;
    float* big = ws + o; o += (size_t)13312000;
    // during GRU (before GAT writes xp1/x1): bf16 weights live in big
    bf16_t* temb_bf = (bf16_t*)big;                       // 30000*320 bf16 = 4.8M floats
    bf16_t* wih0_bf = (bf16_t*)(big + 4800000);           // 768*320 bf16
    bf16_t* whh0_bf = (bf16_t*)(big + 4922880);           // 768*256 bf16
    bf16_t* wih1_bf = (bf16_t*)(big + 5021184);
    bf16_t* whh1_bf = (bf16_t*)(big + 5119488);           // ends 5,217,792
    // VAE (before GRU, offsets >= 9,216,000)
    float* mu  = big + 9216000;
    float* lv  = big + 10240000;
    float* rec = big + 11264000;
    // GAT (after GRU, may overwrite temb/weights)
    float* xp1 = big;                                     // 5,120,000
    float* x1  = big + 5120000;                           // 5,120,000
    float* xp2 = big + 10240000;                          // 1,000,000
    float* x_in = ws + o; o += (size_t)N_ * H_;           // 2,560,000
    unsigned* emax1 = (unsigned*)(ws + o); o += N_ * HEADS_;
    float* den1 = ws + o; o += N_ * HEADS_;
    unsigned* emax2 = (unsigned*)(ws + o); o += N_;
    float* den2 = ws + o; o += N_;
    float* e1   = ws + o; o += (size_t)E2_ * HEADS_;
    float* e2   = ws + o; o += E2_;
    float* asn1 = ws + o; o += N_ * HEADS_;
    float* adn1 = ws + o; o += N_ * HEADS_;
    float* asn2 = ws + o; o += N_;
    float* adn2 = ws + o; o += N_;

    const int TB = 256;
    auto blocks = [](int n) { return (n + 255) / 256; };
    auto gemm_nt = [&](const float* A, const float* Bm, const float* bias, float* C,
                       int M, int N, int K) {
        dim3 g((N + BN - 1) / BN, (M + BM - 1) / BM);
        hipLaunchKernelGGL((gemm_kern<true>), g, dim3(TB), 0, stream, A, Bm, bias, C, M, N, K);
    };
    auto gemm_nn = [&](const float* A, const float* Bm, const float* bias, float* C,
                       int M, int N, int K) {
        dim3 g((N + BN - 1) / BN, (M + BM - 1) / BM);
        hipLaunchKernelGGL((gemm_kern<false>), g, dim3(TB), 0, stream, A, Bm, bias, C, M, N, K);
    };

    // ---- init: zero atomic accumulators + loss slots ----
    hipLaunchKernelGGL(fill_zero, dim3(blocks(180000)), dim3(TB), 0, stream,
                       (float*)emax1, 180000);  // emax1,den1,emax2,den2 contiguous
    hipLaunchKernelGGL(fill_zero, dim3(1), dim3(TB), 0, stream, out + N_ * H2_, 2);

    // ---- bf16 conversions (every launch; weights immutable but no static guards) ----
    hipLaunchKernelGGL(conv_pad_bf16, dim3(blocks(V_ * DP_)), dim3(TB), 0, stream,
                       temb, temb_bf, V_, D_, DP_);
    hipLaunchKernelGGL(conv_pad_bf16, dim3(blocks(3 * H_ * DP_)), dim3(TB), 0, stream,
                       w_ih0, wih0_bf, 3 * H_, D_, DP_);
    hipLaunchKernelGGL(conv_pad_bf16, dim3(blocks(3 * H_ * H_)), dim3(TB), 0, stream,
                       w_hh0, whh0_bf, 3 * H_, H_, H_);
    hipLaunchKernelGGL(conv_pad_bf16, dim3(blocks(3 * H_ * H_)), dim3(TB), 0, stream,
                       w_ih1, wih1_bf, 3 * H_, H_, H_);
    hipLaunchKernelGGL(conv_pad_bf16, dim3(blocks(3 * H_ * H_)), dim3(TB), 0, stream,
                       w_hh1, whh1_bf, 3 * H_, H_, H_);
    hipLaunchKernelGGL(init_h, dim3(blocks(NT_ * H_)), dim3(TB), 0, stream,
                       h0in, h0f, h1f, h0b[0], h1b[0]);

    // ---- VAE (f32) ----
    gemm_nt(user_feats, w_mu, b_mu, mu, NU_, Z_, F_);
    gemm_nt(user_feats, w_lv, b_lv, lv, NU_, Z_, F_);
    float* z = x_in + (size_t)B_ * H_;   // z occupies x_in rows [B_, B_+NU_)
    hipLaunchKernelGGL(vae_z_kl, dim3(blocks(NU_ * Z_)), dim3(TB), 0, stream,
                       mu, lv, veps, z, out + N_ * H2_);
    gemm_nt(z, w_dec, b_dec, rec, NU_, F_, Z_);
    hipLaunchKernelGGL(rec_loss_kern, dim3(blocks(NU_ * F_)), dim3(TB), 0, stream,
                       rec, user_feats, out + N_ * H2_ + 1);

    // ---- 2-layer GRU: 2 fused MFMA kernels per step ----
    dim3 ggrid(H_ / 32, (NT_ + 63) / 64);   // 8 x 94
    for (int t = 0; t < T_; t++) {
        int p = t & 1, q = p ^ 1;
        hipLaunchKernelGGL((gru_step_kern<DP_>), ggrid, dim3(TB), 0, stream,
                           temb_bf, gnf + t, T_, wih0_bf, b_ih0,
                           h0b[p], whh0_bf, b_hh0, h0f, h0b[q]);
        hipLaunchKernelGGL((gru_step_kern<H_>), ggrid, dim3(TB), 0, stream,
                           h0b[q], (const int*)nullptr, 0, wih1_bf, b_ih1,
                           h1b[p], whh1_bf, b_hh1, h1f, h1b[q]);
    }

    // ---- assemble x_in = [hn[:B], z, hn[B:]] (z already in place) ----
    hipLaunchKernelGGL(assemble_xin, dim3(blocks(NT_ * H_)), dim3(TB), 0, stream,
                       h1f, x_in);

    // ---- GAT layer 1 (8 heads x 64, concat) ----
    gemm_nn(x_in, w1, nullptr, xp1, N_, HEADS_ * H1_, H_);
    hipLaunchKernelGGL(gat_attn_coef, dim3(blocks(N_ * HEADS_)), dim3(TB), 0, stream,
                       xp1, a_src1, a_dst1, asn1, adn1, HEADS_, H1_);
    hipLaunchKernelGGL(bias_init, dim3(blocks(N_ * HEADS_ * H1_)), dim3(TB), 0, stream,
                       x1, b1, N_, HEADS_ * H1_);
    hipLaunchKernelGGL(gat_edge_logits, dim3(blocks(E2_ * HEADS_)), dim3(TB), 0, stream,
                       ei, asn1, adn1, e1, emax1, HEADS_);
    hipLaunchKernelGGL(gat_edge_exp, dim3(blocks(E2_ * HEADS_)), dim3(TB), 0, stream,
                       ei, e1, emax1, den1, HEADS_);
    hipLaunchKernelGGL(gat_edge_alpha, dim3(blocks(E2_ * HEADS_)), dim3(TB), 0, stream,
                       ei, e1, den1, HEADS_);
    hipLaunchKernelGGL(gat_edge_agg, dim3(blocks(E2_ * HEADS_ * H1_)), dim3(TB), 0, stream,
                       ei, e1, xp1, x1, HEADS_, H1_);

    // ---- GAT layer 2 (1 head x 100, mean==identity) ----
    gemm_nn(x1, w2, nullptr, xp2, N_, H2_, HEADS_ * H1_);
    hipLaunchKernelGGL(gat_attn_coef, dim3(blocks(N_)), dim3(TB), 0, stream,
                       xp2, a_src2, a_dst2, asn2, adn2, 1, H2_);
    hipLaunchKernelGGL(bias_init, dim3(blocks(N_ * H2_)), dim3(TB), 0, stream,
                       out, b2, N_, H2_);
    hipLaunchKernelGGL(gat_edge_logits, dim3(blocks(E2_)), dim3(TB), 0, stream,
                       ei, asn2, adn2, e2, emax2, 1);
    hipLaunchKernelGGL(gat_edge_exp, dim3(blocks(E2_)), dim3(TB), 0, stream,
                       ei, e2, emax2, den2, 1);
    hipLaunchKernelGGL(gat_edge_alpha, dim3(blocks(E2_)), dim3(TB), 0, stream,
                       ei, e2, den2, 1);
    hipLaunchKernelGGL(gat_edge_agg, dim3(blocks(E2_ * H2_)), dim3(TB), 0, stream,
                       ei, e2, xp2, out, 1, H2_);

    (void)in_sizes; (void)n_in; (void)out_size; (void)ws_size;
}

// Round 3
// 2791.286 us; speedup vs baseline: 3.1963x; 1.1213x over previous
//
#include <hip/hip_runtime.h>

// ---- problem dims (fixed by reference) ----
#define V_ 30000
#define D_ 300
#define DP_ 320         // D padded to multiple of 32 for MFMA K-loop
#define T_ 24
#define H_ 256
#define NT_ 6000
#define NU_ 4000
#define N_ 10000
#define F_ 512
#define Z_ 256
#define E_ 80000
#define B_ 2000
#define H1_ 64
#define H2_ 100
#define HEADS_ 8
#define E2_ (E_ + N_)   // edges + self loops = 90000
#define TCH_ 4          // time-chunk for batched gi GEMMs (T_ % TCH_ == 0)

typedef __bf16 bf16_t;
typedef bf16_t bf16x8 __attribute__((ext_vector_type(8)));
typedef float  f32x4  __attribute__((ext_vector_type(4)));

// =======================================================================
// 128x128-tile MFMA GEMM: C[M,N] = A[M,K](bf16) @ B[N,K](bf16)^T (+bias)
// 4 waves, each owns a 64x64 quadrant = 4x4 16x16x32-MFMA tiles.
// GM=1: A-row r gathers token gnf[(r%NT)*T + (t0 + r/NT)] (embedding lookup).
// OUTBF: write bf16 C (for gi buffers), else f32.
// Direct-from-global fragment loads (B is small + L2-resident; A streamed).
// =======================================================================
template<int GM, bool OUTBF>
__global__ __launch_bounds__(256) void mfma_gemm(
    const bf16_t* __restrict__ A, const bf16_t* __restrict__ B,
    const float* __restrict__ bias, float* __restrict__ Cf,
    bf16_t* __restrict__ Cb, int M, int N, int K, int ldc,
    const int* __restrict__ gtok, int t0)
{
    const int tid  = (int)threadIdx.x;
    const int wave = tid >> 6, lane = tid & 63;
    const int quad = lane >> 4, l16 = lane & 15;
    const int mbase = blockIdx.y * 128 + (wave & 1) * 64;
    const int nbase = blockIdx.x * 128 + (wave >> 1) * 64;

    const bf16_t* arow[4];
#pragma unroll
    for (int mi = 0; mi < 4; mi++) {
        int r = mbase + mi * 16 + l16;
        if (r >= M) r = M - 1;
        int src;
        if (GM == 1) {
            int t = r / NT_;
            int i = r - t * NT_;
            src = gtok[i * T_ + t0 + t];
        } else {
            src = r;
        }
        arow[mi] = A + (size_t)src * K;
    }
    const bf16_t* brow[4];
#pragma unroll
    for (int ni = 0; ni < 4; ni++) {
        int r = nbase + ni * 16 + l16;
        if (r >= N) r = N - 1;
        brow[ni] = B + (size_t)r * K;
    }

    f32x4 acc[4][4];
#pragma unroll
    for (int mi = 0; mi < 4; mi++)
#pragma unroll
        for (int ni = 0; ni < 4; ni++) acc[mi][ni] = (f32x4){0.f, 0.f, 0.f, 0.f};

    for (int k0 = 0; k0 < K; k0 += 32) {
        bf16x8 afr[4], bfr[4];
#pragma unroll
        for (int mi = 0; mi < 4; mi++) afr[mi] = *(const bf16x8*)(arow[mi] + k0 + quad * 8);
#pragma unroll
        for (int ni = 0; ni < 4; ni++) bfr[ni] = *(const bf16x8*)(brow[ni] + k0 + quad * 8);
#pragma unroll
        for (int mi = 0; mi < 4; mi++)
#pragma unroll
            for (int ni = 0; ni < 4; ni++)
                acc[mi][ni] = __builtin_amdgcn_mfma_f32_16x16x32_bf16(
                    afr[mi], bfr[ni], acc[mi][ni], 0, 0, 0);
    }

#pragma unroll
    for (int ni = 0; ni < 4; ni++) {
        int col = nbase + ni * 16 + l16;
        if (col >= N) continue;
        float bv = bias ? bias[col] : 0.f;
#pragma unroll
        for (int mi = 0; mi < 4; mi++)
#pragma unroll
            for (int r = 0; r < 4; r++) {
                int row = mbase + mi * 16 + quad * 4 + r;
                if (row >= M) continue;
                float v = acc[mi][ni][r] + bv;
                if (OUTBF) Cb[(size_t)row * ldc + col] = (bf16_t)v;
                else       Cf[(size_t)row * ldc + col] = v;
            }
    }
}

// =======================================================================
// GRU recurrence-only step: gh = h_prev @ Wh^T (K=256), gi read from global
// (bf16, b_ih already fused), gate math, h written f32 master + bf16 copy.
// Block = 64 rows x 32 h-cols; wave w owns rows [bm+16w, +16).
// =======================================================================
__global__ __launch_bounds__(256) void gru_rec_step(
    const bf16_t* __restrict__ Gi,      // [NT][768] bf16 (with b_ih)
    const bf16_t* __restrict__ Wh,      // [768][256] bf16
    const float* __restrict__ b_hh,
    const bf16_t* __restrict__ hb_prev, // [NT][256] bf16
    float* __restrict__ hf,             // [NT][256] f32 master (read old/write new)
    bf16_t* __restrict__ hb_out)        // [NT][256] bf16
{
    const int tid  = (int)threadIdx.x;
    const int wave = tid >> 6, lane = tid & 63;
    const int quad = lane >> 4, l16 = lane & 15;
    const int bm = blockIdx.y * 64 + wave * 16;
    const int bn = blockIdx.x * 32;

    int mrow = bm + l16;
    int mclamp = mrow < NT_ ? mrow : NT_ - 1;
    const bf16_t* ahRow = hb_prev + (size_t)mclamp * H_;

    f32x4 acc[3][2];
#pragma unroll
    for (int g = 0; g < 3; g++)
#pragma unroll
        for (int f = 0; f < 2; f++) acc[g][f] = (f32x4){0.f, 0.f, 0.f, 0.f};

    for (int k0 = 0; k0 < H_; k0 += 32) {
        bf16x8 a = *(const bf16x8*)(ahRow + k0 + quad * 8);
#pragma unroll
        for (int g = 0; g < 3; g++)
#pragma unroll
            for (int f = 0; f < 2; f++) {
                int wr = g * H_ + bn + f * 16 + l16;
                bf16x8 b = *(const bf16x8*)(Wh + (size_t)wr * H_ + k0 + quad * 8);
                acc[g][f] = __builtin_amdgcn_mfma_f32_16x16x32_bf16(a, b, acc[g][f], 0, 0, 0);
            }
    }

#pragma unroll
    for (int f = 0; f < 2; f++) {
        int col = bn + f * 16 + l16;
        float bhr = b_hh[col], bhz = b_hh[H_ + col], bhn = b_hh[2 * H_ + col];
#pragma unroll
        for (int r = 0; r < 4; r++) {
            int m = bm + quad * 4 + r;
            if (m >= NT_) continue;
            const bf16_t* gim = Gi + (size_t)m * (3 * H_);
            float ir = (float)gim[col];
            float iz = (float)gim[H_ + col];
            float in_ = (float)gim[2 * H_ + col];
            float hr = acc[0][f][r] + bhr;
            float hz = acc[1][f][r] + bhz;
            float hn = acc[2][f][r] + bhn;
            float rg = 1.f / (1.f + expf(-(ir + hr)));
            float zg = 1.f / (1.f + expf(-(iz + hz)));
            float ng = tanhf(in_ + rg * hn);
            size_t off = (size_t)m * H_ + col;
            float hnew = (1.f - zg) * ng + zg * hf[off];
            hf[off] = hnew;
            hb_out[off] = (bf16_t)hnew;
        }
    }
}

// ---------------- conversions ----------------
__global__ void conv_pad_bf16(const float* __restrict__ in, bf16_t* __restrict__ outp,
                              int rows, int cin, int cout)
{
    int i = blockIdx.x * blockDim.x + threadIdx.x;
    if (i >= rows * cout) return;
    int r = i / cout, c = i - r * cout;
    outp[i] = (bf16_t)(c < cin ? in[(size_t)r * cin + c] : 0.f);
}

// out[n][k] = in[k][n]  (convert B from [K][N] to [N][K] bf16)
__global__ void transp_bf16(const float* __restrict__ in, bf16_t* __restrict__ outp,
                            int Nn, int Kk)
{
    int i = blockIdx.x * blockDim.x + threadIdx.x;
    if (i >= Nn * Kk) return;
    int n = i / Kk, k = i - n * Kk;
    outp[i] = (bf16_t)in[(size_t)k * Nn + n];
}

__global__ void init_h(const float* __restrict__ h0in, float* __restrict__ h0f,
                       float* __restrict__ h1f, bf16_t* __restrict__ h0b,
                       bf16_t* __restrict__ h1b)
{
    int i = blockIdx.x * blockDim.x + threadIdx.x;
    if (i >= NT_ * H_) return;
    float a = h0in[i], b = h0in[NT_ * H_ + i];
    h0f[i] = a; h1f[i] = b;
    h0b[i] = (bf16_t)a; h1b[i] = (bf16_t)b;
}

// ---------------- small utility kernels ----------------
__global__ void fill_zero(float* p, int n)
{
    int i = blockIdx.x * blockDim.x + threadIdx.x;
    if (i < n) p[i] = 0.f;
}

__global__ void bias_init(float* __restrict__ outp, const float* __restrict__ bias,
                          int rows, int cols)
{
    int i = blockIdx.x * blockDim.x + threadIdx.x;
    if (i < rows * cols) outp[i] = bias[i % cols];
}

// ---------------- VAE ----------------
__global__ void vae_z_kl(const float* __restrict__ mu, const float* __restrict__ lv,
                         const float* __restrict__ eps, bf16_t* __restrict__ z_out,
                         float* __restrict__ kl_out)
{
    int idx = blockIdx.x * blockDim.x + threadIdx.x;
    float t = 0.f;
    if (idx < NU_ * Z_) {
        float m = mu[idx], l = lv[idx];
        float el = expf(l);
        z_out[idx] = (bf16_t)(m + expf(0.5f * l) * eps[idx]);
        t = -0.5f * (1.f + l - m * m - el);
    }
    __shared__ float red[256];
    red[threadIdx.x] = t;
    __syncthreads();
    for (int s = 128; s > 0; s >>= 1) {
        if ((int)threadIdx.x < s) red[threadIdx.x] += red[threadIdx.x + s];
        __syncthreads();
    }
    if (threadIdx.x == 0) atomicAdd(kl_out, red[0] * (1.f / NU_));
}

__global__ void rec_loss_kern(const float* __restrict__ rec, const float* __restrict__ uf,
                              float* __restrict__ loss_out)
{
    int idx = blockIdx.x * blockDim.x + threadIdx.x;
    float t = 0.f;
    if (idx < NU_ * F_) {
        float d = rec[idx] - uf[idx];
        t = d * d;
    }
    __shared__ float red[256];
    red[threadIdx.x] = t;
    __syncthreads();
    for (int s = 128; s > 0; s >>= 1) {
        if ((int)threadIdx.x < s) red[threadIdx.x] += red[threadIdx.x + s];
        __syncthreads();
    }
    if (threadIdx.x == 0) atomicAdd(loss_out, red[0] * (1.f / (NU_ * F_)));
}

// ---------------- assemble x_in = [hn[:B], z, hn[B:]] (bf16) ----------------
__global__ void assemble_xin(const float* __restrict__ h1, bf16_t* __restrict__ x_in)
{
    int idx = blockIdx.x * blockDim.x + threadIdx.x;
    if (idx >= NT_ * H_) return;
    int row = idx >> 8, col = idx & 255;
    int dst = (row < B_) ? row : (row + NU_);
    x_in[(size_t)dst * H_ + col] = (bf16_t)h1[idx];
}

// ---------------- GAT ----------------
__device__ __forceinline__ unsigned f2sortable(float f)
{
    unsigned u = __float_as_uint(f);
    return (u & 0x80000000u) ? ~u : (u | 0x80000000u);
}
__device__ __forceinline__ float sortable2f(unsigned u)
{
    return (u & 0x80000000u) ? __uint_as_float(u & 0x7FFFFFFFu) : __uint_as_float(~u);
}

__global__ void gat_attn_coef(const float* __restrict__ xp, const float* __restrict__ a_src,
                              const float* __restrict__ a_dst, float* __restrict__ asn,
                              float* __restrict__ adn, int heads, int C)
{
    int i = blockIdx.x * blockDim.x + threadIdx.x;
    if (i >= N_ * heads) return;
    int node = i / heads, h = i - node * heads;
    const float* x = xp + (size_t)(node * heads + h) * C;
    float s = 0.f, d = 0.f;
    for (int c = 0; c < C; c++) {
        float v = x[c];
        s += v * a_src[h * C + c];
        d += v * a_dst[h * C + c];
    }
    asn[i] = s;
    adn[i] = d;
}

__device__ __forceinline__ void edge_sd(const int* __restrict__ ei, int e, int& s, int& d)
{
    if (e < E_) { s = ei[e]; d = ei[E_ + e]; }
    else        { s = d = e - E_; }
}

__global__ void gat_edge_logits(const int* __restrict__ ei, const float* __restrict__ asn,
                                const float* __restrict__ adn, float* __restrict__ ebuf,
                                unsigned* __restrict__ emax, int heads)
{
    int idx = blockIdx.x * blockDim.x + threadIdx.x;
    if (idx >= E2_ * heads) return;
    int e = idx / heads, h = idx - e * heads;
    int s, d; edge_sd(ei, e, s, d);
    float v = asn[s * heads + h] + adn[d * heads + h];
    v = (v > 0.f) ? v : 0.2f * v;
    ebuf[idx] = v;
    atomicMax(emax + d * heads + h, f2sortable(v));
}

__global__ void gat_edge_exp(const int* __restrict__ ei, float* __restrict__ ebuf,
                             const unsigned* __restrict__ emax, float* __restrict__ den,
                             int heads)
{
    int idx = blockIdx.x * blockDim.x + threadIdx.x;
    if (idx >= E2_ * heads) return;
    int e = idx / heads, h = idx - e * heads;
    int s, d; edge_sd(ei, e, s, d);
    float ee = expf(ebuf[idx] - sortable2f(emax[d * heads + h]));
    ebuf[idx] = ee;
    atomicAdd(den + d * heads + h, ee);
}

__global__ void gat_edge_alpha(const int* __restrict__ ei, float* __restrict__ ebuf,
                               const float* __restrict__ den, int heads)
{
    int idx = blockIdx.x * blockDim.x + threadIdx.x;
    if (idx >= E2_ * heads) return;
    int e = idx / heads, h = idx - e * heads;
    int s, d; edge_sd(ei, e, s, d);
    ebuf[idx] = ebuf[idx] / den[d * heads + h];
}

__global__ void gat_edge_agg(const int* __restrict__ ei, const float* __restrict__ alpha,
                             const float* __restrict__ xp, float* __restrict__ outp,
                             int heads, int C)
{
    int idx = blockIdx.x * blockDim.x + threadIdx.x;
    int total = E2_ * heads * C;
    if (idx >= total) return;
    int c = idx % C;
    int t = idx / C;
    int h = t % heads;
    int e = t / heads;
    int s, d; edge_sd(ei, e, s, d);
    float a = alpha[e * heads + h];
    atomicAdd(outp + (size_t)d * heads * C + h * C + c,
              xp[(size_t)s * heads * C + h * C + c] * a);
}

// ---------------- launcher ----------------
extern "C" void kernel_launch(void* const* d_in, const int* in_sizes, int n_in,
                              void* d_out, int out_size, void* d_ws, size_t ws_size,
                              hipStream_t stream)
{
    const float* user_feats = (const float*)d_in[1];
    const int*   gnf        = (const int*)d_in[2];
    const int*   ei         = (const int*)d_in[3];
    const float* temb       = (const float*)d_in[4];
    const float* w_ih0      = (const float*)d_in[5];
    const float* w_hh0      = (const float*)d_in[6];
    const float* b_ih0      = (const float*)d_in[7];
    const float* b_hh0      = (const float*)d_in[8];
    const float* w_ih1      = (const float*)d_in[9];
    const float* w_hh1      = (const float*)d_in[10];
    const float* b_ih1      = (const float*)d_in[11];
    const float* b_hh1      = (const float*)d_in[12];
    const float* h0in       = (const float*)d_in[13];
    const float* w_mu       = (const float*)d_in[14];
    const float* b_mu       = (const float*)d_in[15];
    const float* w_lv       = (const float*)d_in[16];
    const float* b_lv       = (const float*)d_in[17];
    const float* w_dec      = (const float*)d_in[18];
    const float* b_dec      = (const float*)d_in[19];
    const float* veps       = (const float*)d_in[20];
    const float* w1         = (const float*)d_in[21];
    const float* a_src1     = (const float*)d_in[22];
    const float* a_dst1     = (const float*)d_in[23];
    const float* b1         = (const float*)d_in[24];
    const float* w2         = (const float*)d_in[25];
    const float* a_src2     = (const float*)d_in[26];
    const float* a_dst2     = (const float*)d_in[27];
    const float* b2         = (const float*)d_in[28];
    float* out = (float*)d_out;

    // ---- workspace layout (float units) ----
    float* ws = (float*)d_ws;
    size_t o = 0;
    // BIG union region: phase A (VAE+GRU) / phase B (GAT)
    float* big = ws + o; o += (size_t)18200000;
    bf16_t* temb_bf = (bf16_t*)big;                  // 30000*320 bf16 = 4.8M f
    bf16_t* Gi_bf   = (bf16_t*)(big + 4800000);      // TCH*NT*768 bf16 = 9.216M f
    float*  mu      = big + 14016000;                // 1.024M
    float*  lv      = big + 15040000;                // 1.024M
    float*  rec     = big + 16064000;                // 2.048M
    float*  xp1     = big;                           // phase B: 5.12M
    float*  x1      = big + 5120000;                 // 5.12M
    bf16_t* x1b     = (bf16_t*)(big + 10240000);     // 2.56M f
    float*  xp2     = big + 12800000;                // 1.0M
    // persistent
    float*  h0f = ws + o; o += (size_t)NT_ * H_;
    float*  h1f = ws + o; o += (size_t)NT_ * H_;
    bf16_t* h0b_init = (bf16_t*)(ws + o); o += (size_t)NT_ * H_ / 2;
    bf16_t* h1b[2];
    h1b[0] = (bf16_t*)(ws + o); o += (size_t)NT_ * H_ / 2;
    h1b[1] = (bf16_t*)(ws + o); o += (size_t)NT_ * H_ / 2;
    bf16_t* out0 = (bf16_t*)(ws + o); o += (size_t)TCH_ * NT_ * H_ / 2;  // 3.072M f
    bf16_t* xin_bf = (bf16_t*)(ws + o); o += (size_t)N_ * H_ / 2;        // 1.28M f
    bf16_t* wih0_bf = (bf16_t*)(ws + o); o += (size_t)3 * H_ * DP_ / 2;
    bf16_t* whh0_bf = (bf16_t*)(ws + o); o += (size_t)3 * H_ * H_ / 2;
    bf16_t* wih1_bf = (bf16_t*)(ws + o); o += (size_t)3 * H_ * H_ / 2;
    bf16_t* whh1_bf = (bf16_t*)(ws + o); o += (size_t)3 * H_ * H_ / 2;
    bf16_t* ufeats_bf = (bf16_t*)(ws + o); o += (size_t)NU_ * F_ / 2;
    bf16_t* wmu_bf  = (bf16_t*)(ws + o); o += (size_t)Z_ * F_ / 2;
    bf16_t* wlv_bf  = (bf16_t*)(ws + o); o += (size_t)Z_ * F_ / 2;
    bf16_t* wdec_bf = (bf16_t*)(ws + o); o += (size_t)F_ * Z_ / 2;
    bf16_t* w1t_bf  = (bf16_t*)(ws + o); o += (size_t)(HEADS_ * H1_) * H_ / 2;
    bf16_t* w2t_bf  = (bf16_t*)(ws + o); o += (size_t)H2_ * (HEADS_ * H1_) / 2;
    unsigned* emax1 = (unsigned*)(ws + o); o += N_ * HEADS_;
    float* den1 = ws + o; o += N_ * HEADS_;
    unsigned* emax2 = (unsigned*)(ws + o); o += N_;
    float* den2 = ws + o; o += N_;
    float* e1   = ws + o; o += (size_t)E2_ * HEADS_;
    float* e2   = ws + o; o += E2_;
    float* asn1 = ws + o; o += N_ * HEADS_;
    float* adn1 = ws + o; o += N_ * HEADS_;
    float* asn2 = ws + o; o += N_;
    float* adn2 = ws + o; o += N_;

    const int TB = 256;
    auto blocks = [](int n) { return (n + 255) / 256; };
    auto ggrid = [](int M, int N) { return dim3((N + 127) / 128, (M + 127) / 128); };

    // ---- init: zero atomic accumulators + loss slots ----
    hipLaunchKernelGGL(fill_zero, dim3(blocks(180000)), dim3(TB), 0, stream,
                       (float*)emax1, 180000);  // emax1,den1,emax2,den2 contiguous
    hipLaunchKernelGGL(fill_zero, dim3(1), dim3(TB), 0, stream, out + N_ * H2_, 2);

    // ---- bf16 conversions ----
    hipLaunchKernelGGL(conv_pad_bf16, dim3(blocks(V_ * DP_)), dim3(TB), 0, stream,
                       temb, temb_bf, V_, D_, DP_);
    hipLaunchKernelGGL(conv_pad_bf16, dim3(blocks(3 * H_ * DP_)), dim3(TB), 0, stream,
                       w_ih0, wih0_bf, 3 * H_, D_, DP_);
    hipLaunchKernelGGL(conv_pad_bf16, dim3(blocks(3 * H_ * H_)), dim3(TB), 0, stream,
                       w_hh0, whh0_bf, 3 * H_, H_, H_);
    hipLaunchKernelGGL(conv_pad_bf16, dim3(blocks(3 * H_ * H_)), dim3(TB), 0, stream,
                       w_ih1, wih1_bf, 3 * H_, H_, H_);
    hipLaunchKernelGGL(conv_pad_bf16, dim3(blocks(3 * H_ * H_)), dim3(TB), 0, stream,
                       w_hh1, whh1_bf, 3 * H_, H_, H_);
    hipLaunchKernelGGL(conv_pad_bf16, dim3(blocks(NU_ * F_)), dim3(TB), 0, stream,
                       user_feats, ufeats_bf, NU_, F_, F_);
    hipLaunchKernelGGL(conv_pad_bf16, dim3(blocks(Z_ * F_)), dim3(TB), 0, stream,
                       w_mu, wmu_bf, Z_, F_, F_);
    hipLaunchKernelGGL(conv_pad_bf16, dim3(blocks(Z_ * F_)), dim3(TB), 0, stream,
                       w_lv, wlv_bf, Z_, F_, F_);
    hipLaunchKernelGGL(conv_pad_bf16, dim3(blocks(F_ * Z_)), dim3(TB), 0, stream,
                       w_dec, wdec_bf, F_, Z_, Z_);
    hipLaunchKernelGGL(transp_bf16, dim3(blocks(HEADS_ * H1_ * H_)), dim3(TB), 0, stream,
                       w1, w1t_bf, HEADS_ * H1_, H_);
    hipLaunchKernelGGL(transp_bf16, dim3(blocks(H2_ * HEADS_ * H1_)), dim3(TB), 0, stream,
                       w2, w2t_bf, H2_, HEADS_ * H1_);
    hipLaunchKernelGGL(init_h, dim3(blocks(NT_ * H_)), dim3(TB), 0, stream,
                       h0in, h0f, h1f, h0b_init, h1b[0]);

    // ---- VAE (all MFMA) ----
    hipLaunchKernelGGL((mfma_gemm<0, false>), ggrid(NU_, Z_), dim3(TB), 0, stream,
                       ufeats_bf, wmu_bf, b_mu, mu, (bf16_t*)nullptr,
                       NU_, Z_, F_, Z_, (const int*)nullptr, 0);
    hipLaunchKernelGGL((mfma_gemm<0, false>), ggrid(NU_, Z_), dim3(TB), 0, stream,
                       ufeats_bf, wlv_bf, b_lv, lv, (bf16_t*)nullptr,
                       NU_, Z_, F_, Z_, (const int*)nullptr, 0);
    bf16_t* z_bf = xin_bf + (size_t)B_ * H_;  // z occupies x_in rows [B_, B_+NU_)
    hipLaunchKernelGGL(vae_z_kl, dim3(blocks(NU_ * Z_)), dim3(TB), 0, stream,
                       mu, lv, veps, z_bf, out + N_ * H2_);
    hipLaunchKernelGGL((mfma_gemm<0, false>), ggrid(NU_, F_), dim3(TB), 0, stream,
                       z_bf, wdec_bf, b_dec, rec, (bf16_t*)nullptr,
                       NU_, F_, Z_, F_, (const int*)nullptr, 0);
    hipLaunchKernelGGL(rec_loss_kern, dim3(blocks(NU_ * F_)), dim3(TB), 0, stream,
                       rec, user_feats, out + N_ * H2_ + 1);

    // ---- 2-layer GRU: chunked batched gi GEMMs + light recurrence ----
    const int MC = TCH_ * NT_;   // 24000 rows per chunk
    dim3 rgrid(H_ / 32, (NT_ + 63) / 64);
    for (int c = 0; c < T_ / TCH_; c++) {
        int t0 = c * TCH_;
        // layer-0 gi for TCH_ steps: gather(emb) @ w_ih0^T + b_ih0  -> bf16
        hipLaunchKernelGGL((mfma_gemm<1, true>), ggrid(MC, 3 * H_), dim3(TB), 0, stream,
                           temb_bf, wih0_bf, b_ih0, (float*)nullptr, Gi_bf,
                           MC, 3 * H_, DP_, 3 * H_, gnf, t0);
        for (int s = 0; s < TCH_; s++) {
            int t = t0 + s;
            const bf16_t* prev = (t == 0) ? h0b_init
                                          : out0 + (size_t)((t - 1) % TCH_) * NT_ * H_;
            hipLaunchKernelGGL(gru_rec_step, rgrid, dim3(TB), 0, stream,
                               Gi_bf + (size_t)s * NT_ * 3 * H_, whh0_bf, b_hh0,
                               prev, h0f, out0 + (size_t)s * NT_ * H_);
        }
        // layer-1 gi for this chunk: out0 @ w_ih1^T + b_ih1 -> bf16
        hipLaunchKernelGGL((mfma_gemm<0, true>), ggrid(MC, 3 * H_), dim3(TB), 0, stream,
                           out0, wih1_bf, b_ih1, (float*)nullptr, Gi_bf,
                           MC, 3 * H_, H_, 3 * H_, (const int*)nullptr, 0);
        for (int s = 0; s < TCH_; s++) {
            int t = t0 + s;
            hipLaunchKernelGGL(gru_rec_step, rgrid, dim3(TB), 0, stream,
                               Gi_bf + (size_t)s * NT_ * 3 * H_, whh1_bf, b_hh1,
                               h1b[t & 1], h1f, h1b[1 - (t & 1)]);
        }
    }

    // ---- assemble x_in (bf16) = [hn[:B], z, hn[B:]] (z already in place) ----
    hipLaunchKernelGGL(assemble_xin, dim3(blocks(NT_ * H_)), dim3(TB), 0, stream,
                       h1f, xin_bf);

    // ---- GAT layer 1 (8 heads x 64, concat) ----
    hipLaunchKernelGGL((mfma_gemm<0, false>), ggrid(N_, HEADS_ * H1_), dim3(TB), 0, stream,
                       xin_bf, w1t_bf, (const float*)nullptr, xp1, (bf16_t*)nullptr,
                       N_, HEADS_ * H1_, H_, HEADS_ * H1_, (const int*)nullptr, 0);
    hipLaunchKernelGGL(gat_attn_coef, dim3(blocks(N_ * HEADS_)), dim3(TB), 0, stream,
                       xp1, a_src1, a_dst1, asn1, adn1, HEADS_, H1_);
    hipLaunchKernelGGL(bias_init, dim3(blocks(N_ * HEADS_ * H1_)), dim3(TB), 0, stream,
                       x1, b1, N_, HEADS_ * H1_);
    hipLaunchKernelGGL(gat_edge_logits, dim3(blocks(E2_ * HEADS_)), dim3(TB), 0, stream,
                       ei, asn1, adn1, e1, emax1, HEADS_);
    hipLaunchKernelGGL(gat_edge_exp, dim3(blocks(E2_ * HEADS_)), dim3(TB), 0, stream,
                       ei, e1, emax1, den1, HEADS_);
    hipLaunchKernelGGL(gat_edge_alpha, dim3(blocks(E2_ * HEADS_)), dim3(TB), 0, stream,
                       ei, e1, den1, HEADS_);
    hipLaunchKernelGGL(gat_edge_agg, dim3(blocks(E2_ * HEADS_ * H1_)), dim3(TB), 0, stream,
                       ei, e1, xp1, x1, HEADS_, H1_);

    // ---- GAT layer 2 (1 head x 100) ----
    hipLaunchKernelGGL(conv_pad_bf16, dim3(blocks(N_ * HEADS_ * H1_)), dim3(TB), 0, stream,
                       x1, x1b, N_, HEADS_ * H1_, HEADS_ * H1_);
    hipLaunchKernelGGL((mfma_gemm<0, false>), ggrid(N_, H2_), dim3(TB), 0, stream,
                       x1b, w2t_bf, (const float*)nullptr, xp2, (bf16_t*)nullptr,
                       N_, H2_, HEADS_ * H1_, H2_, (const int*)nullptr, 0);
    hipLaunchKernelGGL(gat_attn_coef, dim3(blocks(N_)), dim3(TB), 0, stream,
                       xp2, a_src2, a_dst2, asn2, adn2, 1, H2_);
    hipLaunchKernelGGL(bias_init, dim3(blocks(N_ * H2_)), dim3(TB), 0, stream,
                       out, b2, N_, H2_);
    hipLaunchKernelGGL(gat_edge_logits, dim3(blocks(E2_)), dim3(TB), 0, stream,
                       ei, asn2, adn2, e2, emax2, 1);
    hipLaunchKernelGGL(gat_edge_exp, dim3(blocks(E2_)), dim3(TB), 0, stream,
                       ei, e2, emax2, den2, 1);
    hipLaunchKernelGGL(gat_edge_alpha, dim3(blocks(E2_)), dim3(TB), 0, stream,
                       ei, e2, den2, 1);
    hipLaunchKernelGGL(gat_edge_agg, dim3(blocks(E2_ * H2_)), dim3(TB), 0, stream,
                       ei, e2, xp2, out, 1, H2_);

    (void)in_sizes; (void)n_in; (void)out_size; (void)ws_size;
}